// Round 1
// baseline (328.010 us; speedup 1.0000x reference)
//
#include <hip/hip_runtime.h>
#include <math.h>

// Problem constants (b=8, c=2048, e=64, h=8)
#define NTOK 16384
#define EDIM 64
#define HHE  512   // h*e

// ---------------------------------------------------------------------------
// Kernel 1: q/k/v = x @ W^T + b   (M=16384, N=512 per matrix, K=64)
// grid (256 token-tiles of 64, 4 n-tiles of 128, 3 matrices), block 256
// ---------------------------------------------------------------------------
__global__ __launch_bounds__(256) void qkv_kernel(
    const float* __restrict__ x,
    const float* __restrict__ Wk, const float* __restrict__ bk,
    const float* __restrict__ Wq, const float* __restrict__ bq,
    const float* __restrict__ Wv, const float* __restrict__ bv,
    float* __restrict__ qb, float* __restrict__ kb, float* __restrict__ vb)
{
    __shared__ float xs[64 * 64];        // 16 KB token tile of x
    const int tid  = threadIdx.x;
    const int tok0 = blockIdx.x * 64;
    const int n0   = blockIdx.y * 128;
    const int z    = blockIdx.z;

    #pragma unroll
    for (int i = 0; i < 16; ++i) {
        int idx = i * 256 + tid;         // coalesced copy, layout matches global
        xs[idx] = x[tok0 * 64 + idx];
    }
    __syncthreads();

    const float* W; const float* bias; float* outp;
    if      (z == 0) { W = Wk; bias = bk; outp = kb; }
    else if (z == 1) { W = Wq; bias = bq; outp = qb; }
    else             { W = Wv; bias = bv; outp = vb; }

    const int n     = n0 + (tid & 127);  // output column
    const int tbase = (tid >> 7) * 32;   // token half (uniform per wave)

    float acc[32];
    #pragma unroll
    for (int j = 0; j < 32; ++j) acc[j] = 0.0f;

    const float4* Wrow = (const float4*)(W + n * 64);
    for (int kc = 0; kc < 16; ++kc) {    // K=64 in float4 chunks
        const float4 w4 = Wrow[kc];
        #pragma unroll
        for (int j = 0; j < 32; ++j) {
            const float4 x4 = *(const float4*)&xs[(tbase + j) * 64 + kc * 4]; // LDS broadcast
            acc[j] = fmaf(w4.x, x4.x, acc[j]);
            acc[j] = fmaf(w4.y, x4.y, acc[j]);
            acc[j] = fmaf(w4.z, x4.z, acc[j]);
            acc[j] = fmaf(w4.w, x4.w, acc[j]);
        }
    }
    const float bn = bias[n];
    #pragma unroll
    for (int j = 0; j < 32; ++j)
        outp[(size_t)(tok0 + tbase + j) * HHE + n] = acc[j] + bn;
}

// ---------------------------------------------------------------------------
// Kernel 2: per-token scores -> entmax_bisect -> att @ v
// one wave per token; lane i owns score row i in registers (entmax is
// entirely lane-local). k/v broadcast from LDS. res written over the q
// buffer (safe: token t's q is only read by token t's own wave, earlier).
// ---------------------------------------------------------------------------
__device__ __forceinline__ float pgen(float z, float inv) {
    return z > 0.0f ? exp2f(inv * log2f(fmaxf(z, 1e-30f))) : 0.0f;
}

__global__ __launch_bounds__(256) void attn_kernel(
    float* qb,                    // read q, then write res (alias)
    const float* kb, const float* vb,
    const float* alpha_p)
{
    __shared__ float sK[4][HHE];
    __shared__ float sV[4][HHE];
    const int lane = threadIdx.x & 63;
    const int w    = threadIdx.x >> 6;
    const int tok  = blockIdx.x * 4 + w;

    const float alpha = alpha_p[0];
    const float am1   = alpha - 1.0f;

    float qr[8];
    {
        const float* qp = qb + (size_t)tok * HHE;
        const float* kp = kb + (size_t)tok * HHE;
        const float* vp = vb + (size_t)tok * HHE;
        #pragma unroll
        for (int h = 0; h < 8; ++h) {
            qr[h]                 = qp[h * 64 + lane];   // lane i holds q[h][i]
            sK[w][h * 64 + lane]  = kp[h * 64 + lane];
            sV[w][h * 64 + lane]  = vp[h * 64 + lane];
        }
    }
    __syncthreads();   // make whole-wave LDS writes visible for broadcast reads

    // dot row: row[j] = sum_h q[h][lane] * k[h][j]
    float row[64];
    #pragma unroll
    for (int j = 0; j < 64; ++j) row[j] = 0.0f;
    #pragma unroll
    for (int h = 0; h < 8; ++h) {
        const float qh = qr[h];
        #pragma unroll
        for (int j4 = 0; j4 < 16; ++j4) {
            const float4 k4 = *(const float4*)&sK[w][h * 64 + j4 * 4]; // broadcast
            row[j4*4+0] = fmaf(qh, k4.x, row[j4*4+0]);
            row[j4*4+1] = fmaf(qh, k4.y, row[j4*4+1]);
            row[j4*4+2] = fmaf(qh, k4.z, row[j4*4+2]);
            row[j4*4+3] = fmaf(qh, k4.w, row[j4*4+3]);
        }
    }

    // Xa = dot/sqrt(e) * (alpha-1);  1/8 and am1 fold exactly (pow-of-2)
    const float scale = am1 * 0.125f;
    #pragma unroll
    for (int j = 0; j < 64; ++j) row[j] *= scale;

    float mx = row[0];
    #pragma unroll
    for (int j = 1; j < 64; ++j) mx = fmaxf(mx, row[j]);

    float tau_lo = mx - 1.0f;                         // _gp(1, alpha) = 1
    const float tau_hi = mx - exp2f(-6.0f * am1);     // (1/64)^am1
    float dm = tau_hi - tau_lo;
    float tau_m = tau_lo;

    // Bisection. 24 iters: bracketing gives |tau - root| <= 0.875*2^-24 ~ 5e-8,
    // output-error ~1e-7 << 4.3e-2 threshold (50-iter ref is within fp32 eps of root).
    if (am1 == 0.5f) {
        // alpha = 1.5: p(z) = max(z,0)^2; z <= 1 always (tau >= tau_lo_init),
        // so clamp-to-[0,1] == max(z,0) and folds into the sub's clamp modifier.
        float f_lo = -1.0f;
        #pragma unroll
        for (int j = 0; j < 64; ++j) {
            float zc = fminf(fmaxf(row[j] - tau_lo, 0.0f), 1.0f);
            f_lo = fmaf(zc, zc, f_lo);
        }
        for (int it = 0; it < 24; ++it) {
            dm *= 0.5f;
            tau_m = tau_lo + dm;
            float f = -1.0f;
            #pragma unroll
            for (int j = 0; j < 64; ++j) {
                float zc = fminf(fmaxf(row[j] - tau_m, 0.0f), 1.0f);
                f = fmaf(zc, zc, f);
            }
            tau_lo = (f * f_lo >= 0.0f) ? tau_m : tau_lo;
        }
        float s = 0.0f;
        #pragma unroll
        for (int j = 0; j < 64; ++j) {
            float zc = fminf(fmaxf(row[j] - tau_m, 0.0f), 1.0f);
            zc = zc * zc;
            row[j] = zc;
            s += zc;
        }
        const float rn = 1.0f / s;
        #pragma unroll
        for (int j = 0; j < 64; ++j) row[j] *= rn;
    } else {
        // faithful general-alpha path (unused for this problem's alpha=1.5)
        const float inv = 1.0f / am1;
        float f_lo = -1.0f;
        #pragma unroll
        for (int j = 0; j < 64; ++j) f_lo += pgen(row[j] - tau_lo, inv);
        for (int it = 0; it < 24; ++it) {
            dm *= 0.5f;
            tau_m = tau_lo + dm;
            float f = -1.0f;
            #pragma unroll
            for (int j = 0; j < 64; ++j) f += pgen(row[j] - tau_m, inv);
            tau_lo = (f * f_lo >= 0.0f) ? tau_m : tau_lo;
        }
        float s = 0.0f;
        #pragma unroll
        for (int j = 0; j < 64; ++j) {
            float pm = pgen(row[j] - tau_m, inv);
            row[j] = pm;
            s += pm;
        }
        const float rn = 1.0f / s;
        #pragma unroll
        for (int j = 0; j < 64; ++j) row[j] *= rn;
    }

    // res[h][lane] = sum_j att[lane][j] * v[h][j]
    float acc[8];
    #pragma unroll
    for (int h = 0; h < 8; ++h) acc[h] = 0.0f;
    #pragma unroll
    for (int h = 0; h < 8; ++h) {
        #pragma unroll
        for (int j4 = 0; j4 < 16; ++j4) {
            const float4 v4 = *(const float4*)&sV[w][h * 64 + j4 * 4]; // broadcast
            acc[h] = fmaf(row[j4*4+0], v4.x, acc[h]);
            acc[h] = fmaf(row[j4*4+1], v4.y, acc[h]);
            acc[h] = fmaf(row[j4*4+2], v4.z, acc[h]);
            acc[h] = fmaf(row[j4*4+3], v4.w, acc[h]);
        }
    }
    float* rp = qb + (size_t)tok * HHE;   // res overwrites q (see header comment)
    #pragma unroll
    for (int h = 0; h < 8; ++h) rp[h * 64 + lane] = acc[h];
}

// ---------------------------------------------------------------------------
// Kernel 3: out = res @ Wu^T + bu   (M=16384, N=64, K=512)
// block = 256 threads, 16 tokens per block staged in LDS
// ---------------------------------------------------------------------------
__global__ __launch_bounds__(256) void out_kernel(
    const float* __restrict__ resb, const float* __restrict__ Wu,
    const float* __restrict__ bu, float* __restrict__ out)
{
    __shared__ float rs[16 * HHE];       // 32 KB
    const int tid  = threadIdx.x;
    const int tok0 = blockIdx.x * 16;

    #pragma unroll
    for (int i = 0; i < 8; ++i) {
        int f = i * 256 + tid;           // float4 index, coalesced
        ((float4*)rs)[f] = ((const float4*)(resb + (size_t)tok0 * HHE))[f];
    }
    __syncthreads();

    const int m  = tid & 63;
    const int tg = tid >> 6;             // wave id -> token group (uniform)

    float acc[4] = {0.0f, 0.0f, 0.0f, 0.0f};
    const float4* wrow = (const float4*)(Wu + (size_t)m * HHE);
    for (int o4 = 0; o4 < 128; ++o4) {
        const float4 w4 = wrow[o4];      // L1/L2-hot (Wu is 128 KB, shared)
        #pragma unroll
        for (int t = 0; t < 4; ++t) {
            const float4 r4 = *(const float4*)&rs[(tg * 4 + t) * HHE + o4 * 4]; // broadcast
            acc[t] = fmaf(w4.x, r4.x, acc[t]);
            acc[t] = fmaf(w4.y, r4.y, acc[t]);
            acc[t] = fmaf(w4.z, r4.z, acc[t]);
            acc[t] = fmaf(w4.w, r4.w, acc[t]);
        }
    }
    const float b = bu[m];
    #pragma unroll
    for (int t = 0; t < 4; ++t)
        out[(size_t)(tok0 + tg * 4 + t) * 64 + m] = acc[t] + b;
}

// ---------------------------------------------------------------------------
extern "C" void kernel_launch(void* const* d_in, const int* in_sizes, int n_in,
                              void* d_out, int out_size, void* d_ws, size_t ws_size,
                              hipStream_t stream)
{
    const float* x     = (const float*)d_in[0];
    const float* alpha = (const float*)d_in[1];
    const float* Wk    = (const float*)d_in[2];
    const float* bk    = (const float*)d_in[3];
    const float* Wq    = (const float*)d_in[4];
    const float* bq    = (const float*)d_in[5];
    const float* Wv    = (const float*)d_in[6];
    const float* bv    = (const float*)d_in[7];
    const float* Wu    = (const float*)d_in[8];
    const float* bu    = (const float*)d_in[9];
    float* out = (float*)d_out;

    float* ws = (float*)d_ws;
    float* qb = ws;                                  // 16384*512 floats (res aliases)
    float* kb = ws + (size_t)NTOK * HHE;             // 16384*512
    float* vb = ws + 2 * (size_t)NTOK * HHE;         // 16384*512  (total 96 MB)

    qkv_kernel<<<dim3(NTOK / 64, 4, 3), 256, 0, stream>>>(
        x, Wk, bk, Wq, bq, Wv, bv, qb, kb, vb);
    attn_kernel<<<NTOK / 4, 256, 0, stream>>>(qb, kb, vb, alpha);
    out_kernel<<<NTOK / 16, 256, 0, stream>>>(qb, Wu, bu, out);
}